// Round 8
// baseline (152.672 us; speedup 1.0000x reference)
//
#include <hip/hip_runtime.h>

// Fused causal MHA: B=2, N=2048, D=1024, H=16, dh=64
// Round 8: attn rewritten on 32x32x16 MFMA, swapped QK^T (mfma(K,Q)) so each
// lane owns a full S row slice for q=lane&31; softmax fully in-register;
// P->PV A-frags built via v_cvt_pk_bf16_f32 + shfl_xor(32) (T12) -- no P LDS
// bounce, no lgkmcnt drains in the K-loop. 2 waves x 32q per block, K/V LDS
// staging (double-buffered, swizzled) kept from round 5.

typedef __bf16 bf16x8 __attribute__((ext_vector_type(8)));
typedef float f32x4 __attribute__((ext_vector_type(4)));
typedef float f32x16 __attribute__((ext_vector_type(16)));
typedef unsigned int uint4v __attribute__((ext_vector_type(4)));

#define MFMA16(a, b, c) __builtin_amdgcn_mfma_f32_16x16x32_bf16((a), (b), (c), 0, 0, 0)
#define MFMA32(a, b, c) __builtin_amdgcn_mfma_f32_32x32x16_bf16((a), (b), (c), 0, 0, 0)

__device__ __forceinline__ unsigned short f2bf(float f) {
  __bf16 h = (__bf16)f;                 // hardware RNE cvt
  return *(unsigned short*)&h;
}

__device__ __forceinline__ unsigned cvtpk_bf16(float lo, float hi) {
  unsigned r;
  asm("v_cvt_pk_bf16_f32 %0, %1, %2" : "=v"(r) : "v"(lo), "v"(hi));
  return r;
}

// Build PV A-frag (8 bf16) for one 16-kv chunk from the 16-reg S tile.
// Own-lane regs [base..base+7]; partner half exchanged via shfl_xor(32).
// hi = lane>>5. Derivation: kvt(r,hi) = (r&3)+8*(r>>2)+4*hi (verified C/D
// layout); A-frag needs kv = ck*16 + hi*8 + j.
#define PFRAG(dst, sv, base)                                   \
  do {                                                         \
    const unsigned X0 = cvtpk_bf16((sv)[(base) + 0], (sv)[(base) + 1]); \
    const unsigned X1 = cvtpk_bf16((sv)[(base) + 2], (sv)[(base) + 3]); \
    const unsigned Y0 = cvtpk_bf16((sv)[(base) + 4], (sv)[(base) + 5]); \
    const unsigned Y1 = cvtpk_bf16((sv)[(base) + 6], (sv)[(base) + 7]); \
    const unsigned c0 = __shfl_xor(hi ? X0 : Y0, 32);          \
    const unsigned c1 = __shfl_xor(hi ? X1 : Y1, 32);          \
    uint4v u;                                                  \
    u.x = hi ? c0 : X0; u.y = hi ? c1 : X1;                    \
    u.z = hi ? Y0 : c0; u.w = hi ? Y1 : c1;                    \
    dst = __builtin_bit_cast(bf16x8, u);                       \
  } while (0)

// ---------------- fused prep: cast x, transpose-cast weights ----------------
__global__ __launch_bounds__(256) void prep_kernel(
    const float* __restrict__ x, const float* __restrict__ wqkv,
    const float* __restrict__ wout, unsigned short* __restrict__ xb,
    unsigned short* __restrict__ wqkvT, unsigned short* __restrict__ woutT) {
  __shared__ float tile[32][33];
  const int id = blockIdx.x, t = threadIdx.x;
  if (id < 4096) {
    const int i = id * 256 + t;
    float4 v = ((const float4*)x)[i];
    ushort4 o;
    o.x = f2bf(v.x); o.y = f2bf(v.y); o.z = f2bf(v.z); o.w = f2bf(v.w);
    ((ushort4*)xb)[i] = o;
    return;
  }
  const int tx = t & 31, ty = t >> 5;
  const float* in; unsigned short* out;
  int C, scale_rows, bx, by;
  if (id < 7168) {
    const int q = id - 4096;
    in = wqkv; out = wqkvT; C = 3072; scale_rows = 1024;
    bx = q % 96; by = q / 96;
  } else {
    const int q = id - 7168;
    in = wout; out = woutT; C = 1024; scale_rows = 0;
    bx = q & 31; by = q >> 5;
  }
#pragma unroll
  for (int i = ty; i < 32; i += 8)
    tile[i][tx] = in[(size_t)(by * 32 + i) * C + bx * 32 + tx];
  __syncthreads();
#pragma unroll
  for (int i = ty; i < 32; i += 8) {
    const int orow = bx * 32 + i;
    const float s = (orow < scale_rows) ? 0.18033688f : 1.0f;  // 0.125*log2e
    out[(size_t)orow * 1024 + by * 32 + tx] = f2bf(tile[tx][i] * s);
  }
}

// ------- transpose V region of qkv (bf16) into vT[b][h*64+dim][n] -----------
__global__ void transpose_v_kernel(const unsigned short* __restrict__ qkv,
                                   unsigned short* __restrict__ vT) {
  __shared__ unsigned short tile[32][33];
  const int b = blockIdx.z, bx = blockIdx.x, by = blockIdx.y;
  const int tx = threadIdx.x, ty = threadIdx.y;
#pragma unroll
  for (int i = ty; i < 32; i += 8)
    tile[i][tx] = qkv[(size_t)(b * 2048 + by * 32 + i) * 3072 + 2048 + bx * 32 + tx];
  __syncthreads();
#pragma unroll
  for (int i = ty; i < 32; i += 8)
    vT[((size_t)b * 1024 + bx * 32 + i) * 2048 + by * 32 + tx] = tile[tx][i];
}

// ---------------- 128x128 bf16 GEMM: C = A[M][K] * BT[Nc][K]^T --------------
template <int OUT_BF16>
__global__ __launch_bounds__(256) void gemm128_kernel(
    const unsigned short* __restrict__ A,   // [M][K] bf16
    const unsigned short* __restrict__ BT,  // [Nc][K] bf16
    void* __restrict__ Cp, int M, int Nc, int K) {
  __shared__ unsigned short lA[128 * 32];
  __shared__ unsigned short lB[128 * 32];
  const int t = threadIdx.x;
  const int l = t & 63, g = l >> 4, c = l & 15;
  const int w = t >> 6;
  const int wm = (w >> 1) * 64, wn = (w & 1) * 64;
  const int bm = blockIdx.y * 128, bn = blockIdx.x * 128;

  const int i0 = t, i1 = 256 + t;
  const unsigned short* ga0 = A + (size_t)(bm + (i0 >> 2)) * K + (i0 & 3) * 8;
  const unsigned short* ga1 = A + (size_t)(bm + (i1 >> 2)) * K + (i1 & 3) * 8;
  const unsigned short* gb0 = BT + (size_t)(bn + (i0 >> 2)) * K + (i0 & 3) * 8;
  const unsigned short* gb1 = BT + (size_t)(bn + (i1 >> 2)) * K + (i1 & 3) * 8;
  unsigned short* la0 = lA + (i0 & ~63) * 8;
  unsigned short* la1 = lA + (i1 & ~63) * 8;
  unsigned short* lb0 = lB + (i0 & ~63) * 8;
  unsigned short* lb1 = lB + (i1 & ~63) * 8;

  f32x4 acc[4][4] = {};

  for (int kk = 0; kk < K; kk += 32) {
    __syncthreads();
    __builtin_amdgcn_global_load_lds(
        (const __attribute__((address_space(1))) void*)(ga0 + kk),
        (__attribute__((address_space(3))) void*)la0, 16, 0, 0);
    __builtin_amdgcn_global_load_lds(
        (const __attribute__((address_space(1))) void*)(ga1 + kk),
        (__attribute__((address_space(3))) void*)la1, 16, 0, 0);
    __builtin_amdgcn_global_load_lds(
        (const __attribute__((address_space(1))) void*)(gb0 + kk),
        (__attribute__((address_space(3))) void*)lb0, 16, 0, 0);
    __builtin_amdgcn_global_load_lds(
        (const __attribute__((address_space(1))) void*)(gb1 + kk),
        (__attribute__((address_space(3))) void*)lb1, 16, 0, 0);
    __syncthreads();

    bf16x8 af[4], bfr[4];
#pragma unroll
    for (int mi = 0; mi < 4; ++mi)
      af[mi] = *(const bf16x8*)(lA + (wm + mi * 16 + c) * 32 + g * 8);
#pragma unroll
    for (int ni = 0; ni < 4; ++ni)
      bfr[ni] = *(const bf16x8*)(lB + (wn + ni * 16 + c) * 32 + g * 8);
#pragma unroll
    for (int mi = 0; mi < 4; ++mi)
#pragma unroll
      for (int ni = 0; ni < 4; ++ni)
        acc[mi][ni] = MFMA16(af[mi], bfr[ni], acc[mi][ni]);
  }

  if (OUT_BF16) {
    unsigned short* Cc = (unsigned short*)Cp;
#pragma unroll
    for (int mi = 0; mi < 4; ++mi)
#pragma unroll
      for (int r = 0; r < 4; ++r) {
        const int gr = bm + wm + mi * 16 + g * 4 + r;
#pragma unroll
        for (int ni = 0; ni < 4; ++ni)
          Cc[(size_t)gr * Nc + bn + wn + ni * 16 + c] = f2bf(acc[mi][ni][r]);
      }
  } else {
    float* Cf = (float*)Cp;
#pragma unroll
    for (int mi = 0; mi < 4; ++mi)
#pragma unroll
      for (int r = 0; r < 4; ++r) {
        const int gr = bm + wm + mi * 16 + g * 4 + r;
#pragma unroll
        for (int ni = 0; ni < 4; ++ni)
          Cf[(size_t)gr * Nc + bn + wn + ni * 16 + c] = acc[mi][ni][r];
      }
  }
}

// ---------------- flash attention (causal, swapped QK^T, 32x32) -------------
// 1024 blocks (XCD-clustered heads, big tiles first). Block = 2 waves x 32 q
// = 64 q rows. Full 64-kv blocks staged in double-buffered LDS; diagonal as
// 1-2 wave-divergent masked 32-kv tiles from global.
__global__ __launch_bounds__(128, 2) void attn_kernel(
    const unsigned short* __restrict__ qkv,  // [4096][3072] bf16 (Q|K|V)
    const unsigned short* __restrict__ vT,   // [2][1024][2048] bf16
    unsigned short* __restrict__ aout) {     // [4096][1024] bf16
  const int t = threadIdx.x;            // 0..127
  const int w = t >> 6;                 // wave 0/1
  const int l = t & 63;
  const int col = l & 31;
  const int hi = l >> 5;
  const int hi4 = hi * 4;
  const int c7 = col & 7;

  const int id0 = blockIdx.x;              // 0..1023
  const int xcd = id0 & 7, pos = id0 >> 3;
  const int bh = xcd * 4 + (pos & 3);      // 4 heads per XCD
  const int T = 31 - (pos >> 2);           // big tiles first
  const int b = bh >> 4, h = bh & 15;

  __shared__ __align__(16) unsigned short lK[2][64][64];  // 16 KB
  __shared__ __align__(16) unsigned short lV[2][64][64];  // 16 KB

  const unsigned short* Qbase = qkv + (size_t)b * 2048 * 3072 + h * 64;
  const unsigned short* Kb = Qbase + 1024;
  const unsigned short* Vb = vT + ((size_t)b * 1024 + h * 64) * 2048;

#define STAGE(dK, dV, kb_)                                                    \
  do {                                                                        \
    _Pragma("unroll")                                                         \
    for (int qq = 0; qq < 4; ++qq) {                                          \
      const int idx = qq * 128 + t;                                           \
      const int row = idx >> 3, ch = idx & 7;                                 \
      const int sc = (ch ^ (row & 7)) * 8;                                    \
      __builtin_amdgcn_global_load_lds(                                       \
          (const __attribute__((address_space(1))) void*)(                    \
              Kb + (size_t)(kb_ + row) * 3072 + sc),                          \
          (__attribute__((address_space(3))) void*)(                          \
              &(dK)[0][0] + (idx & ~63) * 8), 16, 0, 0);                      \
      __builtin_amdgcn_global_load_lds(                                       \
          (const __attribute__((address_space(1))) void*)(                    \
              Vb + (size_t)row * 2048 + (kb_) + sc),                          \
          (__attribute__((address_space(3))) void*)(                          \
              &(dV)[0][0] + (idx & ~63) * 8), 16, 0, 0);                      \
    }                                                                         \
  } while (0)

  const int q0w = T * 64 + w * 32;
  const int qg = q0w + col;

  // Q B-frags: col = q = lane&31, k = d = c16*16 + hi*8 + j
  bf16x8 bq[4];
#pragma unroll
  for (int c16 = 0; c16 < 4; ++c16)
    bq[c16] = *(const bf16x8*)(Qbase + (size_t)qg * 3072 + c16 * 16 + hi * 8);

  f32x16 o0 = {}, o1 = {};
  float m_c = -__builtin_inff(), llp = 0.f;

  if (T > 0) {
    STAGE(lK[0], lV[0], 0);
    int cur = 0;
#pragma unroll 1
    for (int jb = 0; jb < T; ++jb) {
      __syncthreads();   // drains stage(cur) vmcnt + prev compute
      if (jb + 1 < T) STAGE(lK[cur ^ 1], lV[cur ^ 1], (jb + 1) * 64);

      const unsigned short* lk = &lK[cur][0][0];
      const unsigned short* lv = &lV[cur][0][0];

      // QK^T: s0 = kv 0-31, s1 = kv 32-63 (S^T: lane col = q)
      f32x16 s0 = {}, s1 = {};
      __builtin_amdgcn_s_setprio(1);
#pragma unroll
      for (int c16 = 0; c16 < 4; ++c16) {
        const int chl = c16 * 2 + hi;
        const bf16x8 k0 = *(const bf16x8*)(lk + (col)*64 + ((chl ^ c7) * 8));
        const bf16x8 k1 = *(const bf16x8*)(lk + (32 + col) * 64 + ((chl ^ c7) * 8));
        s0 = MFMA32(k0, bq[c16], s0);
        s1 = MFMA32(k1, bq[c16], s1);
      }
      __builtin_amdgcn_s_setprio(0);

      // ---- in-register softmax over 64 kv (exp2 domain) ----
      float a[16];
#pragma unroll
      for (int i = 0; i < 16; ++i) a[i] = fmaxf(s0[i], s1[i]);
#pragma unroll
      for (int kk = 8; kk; kk >>= 1)
#pragma unroll
        for (int i = 0; i < kk; ++i) a[i] = fmaxf(a[i], a[i + kk]);
      const float vml = fmaxf(a[0], __shfl_xor(a[0], 32));  // full row max

      if (!__all(vml - m_c <= 5.0f)) {   // rare: rescale
        const float mn = fmaxf(m_c, vml);
        const float al = exp2f(m_c - mn);
        m_c = mn; llp *= al;
#pragma unroll
        for (int r = 0; r < 16; ++r) {
          const float alr = __shfl(al, (r & 3) + 8 * (r >> 2) + hi4);
          o0[r] *= alr; o1[r] *= alr;
        }
      }

#pragma unroll
      for (int i = 0; i < 16; ++i) {
        s0[i] = exp2f(s0[i] - m_c);
        s1[i] = exp2f(s1[i] - m_c);
      }
      float sm[16];
#pragma unroll
      for (int i = 0; i < 16; ++i) sm[i] = s0[i] + s1[i];
#pragma unroll
      for (int kk = 8; kk; kk >>= 1)
#pragma unroll
        for (int i = 0; i < kk; ++i) sm[i] += sm[i + kk];
      llp += sm[0];

      // ---- P -> A-frags in-register (no LDS) ----
      bf16x8 pf0, pf1, pf2, pf3;
      PFRAG(pf0, s0, 0); PFRAG(pf1, s0, 8);
      PFRAG(pf2, s1, 0); PFRAG(pf3, s1, 8);

      __builtin_amdgcn_s_setprio(1);
#pragma unroll
      for (int ck = 0; ck < 4; ++ck) {
        const int chl = ck * 2 + hi;
        const bf16x8 v0 = *(const bf16x8*)(lv + (col)*64 + ((chl ^ c7) * 8));
        const bf16x8 v1 = *(const bf16x8*)(lv + (32 + col) * 64 + ((chl ^ c7) * 8));
        const bf16x8 pf = (ck == 0) ? pf0 : (ck == 1) ? pf1 : (ck == 2) ? pf2 : pf3;
        o0 = MFMA32(pf, v0, o0);
        o1 = MFMA32(pf, v1, o1);
      }
      __builtin_amdgcn_s_setprio(0);
      cur ^= 1;
    }
  }

  // ---- diagonal: wave-divergent 32-kv tiles, direct global ----
  for (int j = 0; j <= w; ++j) {
    const int kb = T * 64 + j * 32;
    const bool masked = (j == w);

    f32x16 s = {};
#pragma unroll
    for (int c16 = 0; c16 < 4; ++c16) {
      const bf16x8 kf = *(const bf16x8*)(Kb + (size_t)(kb + col) * 3072 + c16 * 16 + hi * 8);
      s = MFMA32(kf, bq[c16], s);
    }

    if (masked) {
#pragma unroll
      for (int r = 0; r < 16; ++r) {
        const int kvg = kb + (r & 3) + 8 * (r >> 2) + hi4;
        s[r] = (kvg <= qg) ? s[r] : -__builtin_inff();
      }
    }

    float a[16];
#pragma unroll
    for (int i = 0; i < 16; ++i) a[i] = s[i];
#pragma unroll
    for (int kk = 8; kk; kk >>= 1)
#pragma unroll
      for (int i = 0; i < kk; ++i) a[i] = fmaxf(a[i], a[i + kk]);
    const float vml = fmaxf(a[0], __shfl_xor(a[0], 32));

    if (!__all(vml - m_c <= 5.0f)) {
      const float mn = fmaxf(m_c, vml);
      const float al = exp2f(m_c - mn);
      m_c = mn; llp *= al;
#pragma unroll
      for (int r = 0; r < 16; ++r) {
        const float alr = __shfl(al, (r & 3) + 8 * (r >> 2) + hi4);
        o0[r] *= alr; o1[r] *= alr;
      }
    }

#pragma unroll
    for (int i = 0; i < 16; ++i) s[i] = exp2f(s[i] - m_c);
    float sm[16];
#pragma unroll
    for (int i = 0; i < 16; ++i) sm[i] = s[i];
#pragma unroll
    for (int kk = 8; kk; kk >>= 1)
#pragma unroll
      for (int i = 0; i < kk; ++i) sm[i] += sm[i + kk];
    llp += sm[0];

    bf16x8 pf0, pf1;
    PFRAG(pf0, s, 0); PFRAG(pf1, s, 8);
#pragma unroll
    for (int ck = 0; ck < 2; ++ck) {
      const bf16x8 v0 = *(const bf16x8*)(Vb + (size_t)(col)*2048 + kb + ck * 16 + hi * 8);
      const bf16x8 v1 = *(const bf16x8*)(Vb + (size_t)(32 + col) * 2048 + kb + ck * 16 + hi * 8);
      const bf16x8 pf = ck ? pf1 : pf0;
      o0 = MFMA32(pf, v0, o0);
      o1 = MFMA32(pf, v1, o1);
    }
  }

  // ---- finalize ----
  const float ll = llp + __shfl_xor(llp, 32);
  const float inv = 1.0f / ll;
#pragma unroll
  for (int r = 0; r < 16; ++r) {
    const int qrow = (r & 3) + 8 * (r >> 2) + hi4;
    const float invr = __shfl(inv, qrow);
    const size_t row = (size_t)(b * 2048 + q0w + qrow);
    aout[row * 1024 + h * 64 + col] = f2bf(o0[r] * invr);
    aout[row * 1024 + h * 64 + 32 + col] = f2bf(o1[r] * invr);
  }
#undef STAGE
}

// ---------------------------------------------------------------------------
extern "C" void kernel_launch(void* const* d_in, const int* in_sizes, int n_in,
                              void* d_out, int out_size, void* d_ws, size_t ws_size,
                              hipStream_t stream) {
  const float* x = (const float*)d_in[0];      // [2,2048,1024]
  const float* wqkv = (const float*)d_in[1];   // [1024,3072]
  const float* wout = (const float*)d_in[2];   // [1024,1024]
  float* out = (float*)d_out;                  // [2,2048,1024] f32

  unsigned short* ws = (unsigned short*)d_ws;
  unsigned short* xb = ws;                                  // 4096*1024
  unsigned short* wqkvT = xb + (size_t)4096 * 1024;         // 3072*1024
  unsigned short* woutT = wqkvT + (size_t)3072 * 1024;      // 1024*1024
  unsigned short* qkv = woutT + (size_t)1024 * 1024;        // 4096*3072
  unsigned short* vT = qkv + (size_t)4096 * 3072;           // 2*1024*2048
  unsigned short* aout = vT + (size_t)2 * 1024 * 2048;      // 4096*1024

  prep_kernel<<<8192, 256, 0, stream>>>(x, wqkv, wout, xb, wqkvT, woutT);
  gemm128_kernel<1><<<dim3(24, 32), 256, 0, stream>>>(xb, wqkvT, qkv, 4096, 3072, 1024);
  transpose_v_kernel<<<dim3(32, 64, 2), dim3(32, 8), 0, stream>>>(qkv, vT);
  attn_kernel<<<1024, 128, 0, stream>>>(qkv, vT, aout);
  gemm128_kernel<0><<<dim3(8, 32), 256, 0, stream>>>(aout, woutT, out, 4096, 1024, 1024);
}